// Round 2
// baseline (390.197 us; speedup 1.0000x reference)
//
#include <hip/hip_runtime.h>
#include <stdint.h>

#define N_NODES 100000
#define N_EDGES 1600000
#define IN_DIM 32
#define OUT_DIM 64
#define N_REL 8
#define NSEG (N_NODES * N_REL)     // 800000
#define EPS 1e-10f
#define N_KK 9                      // K-tiles of 32 (8 rel + 1 self)
#define SWG_ELEMS (N_KK * 4 * 64 * 8)  // 18432 bf16 in b-frag order

// counting-sort scan geometry
#define SCAN_ELEMS 4096                         // elements per scan block (256 thr x 16)
#define SCAN_NB ((NSEG + SCAN_ELEMS - 1) / SCAN_ELEMS)  // 196 (fits one 256-thr block in pass 2)

typedef __attribute__((ext_vector_type(8))) short bf16x8;
typedef __attribute__((ext_vector_type(4))) float f32x4;

static __device__ __forceinline__ float bflo(uint32_t u) { return __uint_as_float(u << 16); }
static __device__ __forceinline__ float bfhi(uint32_t u) { return __uint_as_float(u & 0xffff0000u); }
static __device__ __forceinline__ uint16_t f2bf(float f) {
    uint32_t u = __float_as_uint(f);
    return (uint16_t)((u + 0x7fffu + ((u >> 16) & 1u)) >> 16); // RNE
}

// ---------------------------------------------------------------------------
// Dtype probe (earlier rounds proved fp32; kept for robustness, ~3us).
// ---------------------------------------------------------------------------
__global__ __launch_bounds__(256) void detect_kernel(const uint32_t* __restrict__ xw,
                                                     int* __restrict__ flag) {
    __shared__ int cnt;
    if (threadIdx.x == 0) cnt = 0;
    __syncthreads();
    int c = 0;
    for (int k = threadIdx.x; k < 4096; k += 256) {
        uint32_t w = xw[k];
        uint32_t e = (w >> 7) & 0xffu;
        c += (e >= 160u) ? 1 : 0;
    }
    atomicAdd(&cnt, c);
    __syncthreads();
    if (threadIdx.x == 0) *flag = (cnt > 64) ? 1 : 0;  // 1 = fp32 inputs
}

// ---------------------------------------------------------------------------
// prep: swizzle W = [Wl ; Ws] into b-frag order once. Fuses bias add.
// ---------------------------------------------------------------------------
__global__ __launch_bounds__(256) void prep_kernel(const void* __restrict__ Wl,
                                                   const void* __restrict__ Ws,
                                                   const void* __restrict__ bl,
                                                   const void* __restrict__ bs,
                                                   const int* __restrict__ flag,
                                                   uint16_t* __restrict__ sWg,
                                                   float* __restrict__ biasv) {
    int f32 = *flag;
    int idx = blockIdx.x * 256 + threadIdx.x;
    if (idx < SWG_ELEMS) {
        int j    = idx & 7;
        int lane = (idx >> 3) & 63;
        int ot   = (idx >> 9) & 3;
        int kk   = idx >> 11;
        int quad = lane >> 4;
        int k = kk * 32 + quad * 8 + j;
        int o = ot * 16 + (lane & 15);
        if (f32) {
            float v = (k < 256) ? ((const float*)Wl)[(size_t)k * OUT_DIM + o]
                                : ((const float*)Ws)[(size_t)(k - 256) * OUT_DIM + o];
            sWg[idx] = f2bf(v);
        } else {
            sWg[idx] = (k < 256) ? ((const uint16_t*)Wl)[(size_t)k * OUT_DIM + o]
                                 : ((const uint16_t*)Ws)[(size_t)(k - 256) * OUT_DIM + o];
        }
    } else if (idx < SWG_ELEMS + OUT_DIM) {
        int o = idx - SWG_ELEMS;
        if (f32) biasv[o] = ((const float*)bl)[o] + ((const float*)bs)[o];
        else     biasv[o] = bflo((uint32_t)((const uint16_t*)bl)[o])
                          + bflo((uint32_t)((const uint16_t*)bs)[o]);
    }
}

// ---------------------------------------------------------------------------
// CSR build step 1: histogram of segment sizes. 1.6M fire-and-forget u32
// atomics (vs 27.2M of the old scatter).
// ---------------------------------------------------------------------------
__global__ __launch_bounds__(256) void hist_kernel(const int* __restrict__ el,
                                                   uint32_t* __restrict__ cnt) {
    int e = blockIdx.x * 256 + threadIdx.x;
    if (e >= N_EDGES) return;
    int dst = el[e * 3 + 1];
    int rel = el[e * 3 + 2];
    atomicAdd(&cnt[dst * N_REL + rel], 1u);
}

// ---------------------------------------------------------------------------
// CSR build step 2a: per-block sums of counts (SCAN_ELEMS per block).
// ---------------------------------------------------------------------------
__global__ __launch_bounds__(256) void scan1_kernel(const uint32_t* __restrict__ cnt,
                                                    uint32_t* __restrict__ bsum) {
    int base = blockIdx.x * SCAN_ELEMS + threadIdx.x * 16;
    uint32_t s = 0;
    #pragma unroll
    for (int j = 0; j < 16; ++j) {
        int i = base + j;
        s += (i < NSEG) ? cnt[i] : 0u;
    }
    __shared__ uint32_t ls[256];
    ls[threadIdx.x] = s;
    __syncthreads();
    #pragma unroll
    for (int off = 128; off > 0; off >>= 1) {
        if (threadIdx.x < off) ls[threadIdx.x] += ls[threadIdx.x + off];
        __syncthreads();
    }
    if (threadIdx.x == 0) bsum[blockIdx.x] = ls[0];
}

// ---------------------------------------------------------------------------
// CSR build step 2b: exclusive scan of the SCAN_NB (=196) block sums.
// ---------------------------------------------------------------------------
__global__ __launch_bounds__(256) void scan2_kernel(uint32_t* __restrict__ bsum) {
    __shared__ uint32_t ls[256];
    int tid = threadIdx.x;
    ls[tid] = (tid < SCAN_NB) ? bsum[tid] : 0u;
    __syncthreads();
    if (tid == 0) {
        uint32_t run = 0;
        for (int i = 0; i < SCAN_NB; ++i) { uint32_t c = ls[i]; ls[i] = run; run += c; }
    }
    __syncthreads();
    if (tid < SCAN_NB) bsum[tid] = ls[tid];
}

// ---------------------------------------------------------------------------
// CSR build step 2c: in-block exclusive scan + block offset -> ptr & cursor.
// ---------------------------------------------------------------------------
__global__ __launch_bounds__(256) void scan3_kernel(const uint32_t* __restrict__ bsum,
                                                    uint32_t* __restrict__ ptr,
                                                    uint32_t* __restrict__ cursor) {
    int tid = threadIdx.x;
    int base = blockIdx.x * SCAN_ELEMS + tid * 16;
    uint32_t v[16];
    uint32_t run = 0;
    #pragma unroll
    for (int j = 0; j < 16; ++j) {
        int i = base + j;
        uint32_t c = (i < NSEG) ? cursor[i] : 0u;  // cursor currently holds counts
        v[j] = run;
        run += c;
    }
    __shared__ uint32_t ls[256];
    ls[tid] = run;
    __syncthreads();
    // Hillis-Steele inclusive scan over 256 thread totals
    for (int off = 1; off < 256; off <<= 1) {
        uint32_t t = (tid >= off) ? ls[tid - off] : 0u;
        __syncthreads();
        ls[tid] += t;
        __syncthreads();
    }
    uint32_t texcl = ls[tid] - run;
    uint32_t boff = bsum[blockIdx.x];
    #pragma unroll
    for (int j = 0; j < 16; ++j) {
        int i = base + j;
        if (i < NSEG) {
            uint32_t val = boff + texcl + v[j];
            ptr[i]    = val;
            cursor[i] = val;   // running cursor for the sort pass
        }
    }
    if (blockIdx.x == 0 && tid == 0) ptr[NSEG] = N_EDGES;
}

// ---------------------------------------------------------------------------
// CSR build step 3: scatter (src, w) into segment-sorted order.
// 1.6M u32 atomics-with-return + 12.8MB of 8B writes (L3-absorbed).
// ---------------------------------------------------------------------------
__global__ __launch_bounds__(256) void sort_kernel(const int* __restrict__ el,
                                                   const void* __restrict__ ew,
                                                   const int* __restrict__ flag,
                                                   uint32_t* __restrict__ cursor,
                                                   uint2* __restrict__ sorted) {
    int e = blockIdx.x * 256 + threadIdx.x;
    if (e >= N_EDGES) return;
    int src = el[e * 3 + 0];
    int dst = el[e * 3 + 1];
    int rel = el[e * 3 + 2];
    float w = (*flag) ? ((const float*)ew)[e]
                      : bflo((uint32_t)((const uint16_t*)ew)[e]);
    int seg = dst * N_REL + rel;
    uint32_t pos = atomicAdd(&cursor[seg], 1u);
    sorted[pos] = make_uint2((uint32_t)src, __float_as_uint(w));
}

// ---------------------------------------------------------------------------
// Gather-aggregate: 16 lanes per segment, fp32 accumulation in registers,
// fused 1/(den+eps) normalization, single coalesced bf16 write per segment.
// ZERO atomics. x (12.8MB) is L3-resident -> gathers hit cache.
// ---------------------------------------------------------------------------
__global__ __launch_bounds__(256) void agg_kernel(const uint32_t* __restrict__ ptr,
                                                  const uint2* __restrict__ sorted,
                                                  const void* __restrict__ x,
                                                  const int* __restrict__ flag,
                                                  uint32_t* __restrict__ num) {
    int t = blockIdx.x * 256 + threadIdx.x;
    int g = t >> 4;          // segment id
    int p = t & 15;          // feature-pair index
    if (g >= NSEG) return;
    int f32 = *flag;
    int beg = (int)ptr[g];
    int end = (int)ptr[g + 1];
    float a0 = 0.f, a1 = 0.f, sw = 0.f;
    for (int i = beg; i < end; ++i) {
        uint2 d = sorted[i];                     // broadcast across the 16 lanes
        float w = __uint_as_float(d.y);
        float x0, x1;
        if (f32) {
            const float2 v = *(const float2*)((const float*)x + (size_t)d.x * IN_DIM + 2 * p);
            x0 = v.x; x1 = v.y;
        } else {
            uint32_t u = *(const uint32_t*)((const uint16_t*)x + (size_t)d.x * IN_DIM + 2 * p);
            x0 = bflo(u); x1 = bfhi(u);
        }
        a0 += w * x0;
        a1 += w * x1;
        sw += w;
    }
    float inv = 1.0f / (sw + EPS);               // empty segment -> 0/(eps) = 0
    uint32_t packed = (uint32_t)f2bf(a0 * inv) | ((uint32_t)f2bf(a1 * inv) << 16);
    num[(size_t)g * 16 + p] = packed;
}

// ---------------------------------------------------------------------------
// Dense MFMA GEMM: C[100000x64] = [norm_num | x] * W + bias, relu.
// num is already normalized bf16 -> A-fragments are straight bf16x8 loads.
// MFMA layouts (HW-verified): A[m=lane&15][k=quad*8+j]; B[k][n=lane&15];
// C row=quad*4+reg, col=lane&15.
// ---------------------------------------------------------------------------
__global__ __launch_bounds__(256) void dense_mfma_kernel(
    const uint16_t* __restrict__ num16,
    const void* __restrict__ x,
    const uint16_t* __restrict__ sWg,
    const float* __restrict__ biasv,
    const int* __restrict__ flag,
    void* __restrict__ out)
{
    __shared__ uint16_t sB[SWG_ELEMS]; // 36KB
    int f32 = *flag;

    #pragma unroll
    for (int it = 0; it < SWG_ELEMS / (256 * 8); ++it) {   // 9 iterations
        int idx = (it * 256 + threadIdx.x) * 8;
        *(bf16x8*)(sB + idx) = *(const bf16x8*)(sWg + idx);
    }
    __syncthreads();

    int wid  = threadIdx.x >> 6;
    int lane = threadIdx.x & 63;
    int quad = lane >> 4;
    int m    = lane & 15;

    int n0 = blockIdx.x * 64 + wid * 16;
    int n  = n0 + m;
    int nc = (n < N_NODES) ? n : (N_NODES - 1);

    float bias[4];
    #pragma unroll
    for (int ot = 0; ot < 4; ++ot) bias[ot] = biasv[ot * 16 + m];

    f32x4 acc[4];
    #pragma unroll
    for (int ot = 0; ot < 4; ++ot) acc[ot] = (f32x4){0.f, 0.f, 0.f, 0.f};

    #pragma unroll
    for (int kk = 0; kk < N_KK; ++kk) {
        bf16x8 a;
        if (kk < 8) {
            a = *(const bf16x8*)(num16 + ((size_t)nc * 8 + kk) * 32 + quad * 8);
        } else {
            if (f32) {
                const float* base = (const float*)x + (size_t)nc * IN_DIM + quad * 8;
                float4 v0 = *(const float4*)base;
                float4 v1 = *(const float4*)(base + 4);
                a[0] = (short)f2bf(v0.x); a[1] = (short)f2bf(v0.y);
                a[2] = (short)f2bf(v0.z); a[3] = (short)f2bf(v0.w);
                a[4] = (short)f2bf(v1.x); a[5] = (short)f2bf(v1.y);
                a[6] = (short)f2bf(v1.z); a[7] = (short)f2bf(v1.w);
            } else {
                a = *(const bf16x8*)((const uint16_t*)x + (size_t)nc * IN_DIM + quad * 8);
            }
        }
        #pragma unroll
        for (int ot = 0; ot < 4; ++ot) {
            bf16x8 b = *(const bf16x8*)(sB + ((kk * 4 + ot) * 64 + lane) * 8);
            acc[ot] = __builtin_amdgcn_mfma_f32_16x16x32_bf16(a, b, acc[ot], 0, 0, 0);
        }
    }

    #pragma unroll
    for (int ot = 0; ot < 4; ++ot) {
        #pragma unroll
        for (int reg = 0; reg < 4; ++reg) {
            int node = n0 + quad * 4 + reg;
            if (node >= N_NODES) continue;
            int o = ot * 16 + m;
            float v = fmaxf(acc[ot][reg] + bias[ot], 0.0f);
            if (f32) ((float*)out)[(size_t)node * OUT_DIM + o] = v;
            else     ((uint16_t*)out)[(size_t)node * OUT_DIM + o] = f2bf(v);
        }
    }
}

// ===========================================================================
extern "C" void kernel_launch(void* const* d_in, const int* in_sizes, int n_in,
                              void* d_out, int out_size, void* d_ws, size_t ws_size,
                              hipStream_t stream) {
    const void* x  = d_in[0];
    const int* el  = (const int*)d_in[1];
    const void* ew = d_in[2];
    const void* Wl = d_in[3];
    const void* bl = d_in[4];
    const void* Ws = d_in[5];
    const void* bs = d_in[6];

    // workspace:
    // [flag 64B][ptr (NSEG+1)*4][cursor NSEG*4][bsum 16KB][sorted 12.8MB]
    // [num 51.2MB bf16][sWg 36KB][biasv 256B]   total ~70.5MB
    const size_t OFF_PTR  = 64;
    const size_t OFF_CUR  = OFF_PTR + (((size_t)(NSEG + 1) * 4 + 63) & ~(size_t)63);
    const size_t OFF_BS   = OFF_CUR + (size_t)NSEG * 4;
    const size_t OFF_SORT = OFF_BS + 16384;
    const size_t OFF_NUM  = OFF_SORT + (size_t)N_EDGES * 8;
    const size_t OFF_SWG  = OFF_NUM + (size_t)NSEG * IN_DIM * 2;
    const size_t OFF_BIAS = OFF_SWG + (size_t)SWG_ELEMS * 2;
    const size_t REQ      = OFF_BIAS + OUT_DIM * 4;
    if (ws_size < REQ) return;

    int*      flag   = (int*)d_ws;
    uint32_t* ptr    = (uint32_t*)((char*)d_ws + OFF_PTR);
    uint32_t* cursor = (uint32_t*)((char*)d_ws + OFF_CUR);
    uint32_t* bsum   = (uint32_t*)((char*)d_ws + OFF_BS);
    uint2*    sorted = (uint2*)((char*)d_ws + OFF_SORT);
    uint32_t* num    = (uint32_t*)((char*)d_ws + OFF_NUM);
    uint16_t* sWg    = (uint16_t*)((char*)d_ws + OFF_SWG);
    float*    biasv  = (float*)((char*)d_ws + OFF_BIAS);

    // only the histogram bins need zeroing (3.2MB vs the old 54.6MB)
    (void)hipMemsetAsync(cursor, 0, (size_t)NSEG * 4, stream);

    detect_kernel<<<1, 256, 0, stream>>>((const uint32_t*)x, flag);
    prep_kernel<<<(SWG_ELEMS + OUT_DIM + 255) / 256, 256, 0, stream>>>(Wl, Ws, bl, bs, flag, sWg, biasv);

    const int eblocks = (N_EDGES + 255) / 256;  // 6250
    hist_kernel<<<eblocks, 256, 0, stream>>>(el, cursor);
    scan1_kernel<<<SCAN_NB, 256, 0, stream>>>(cursor, bsum);
    scan2_kernel<<<1, 256, 0, stream>>>(bsum);
    scan3_kernel<<<SCAN_NB, 256, 0, stream>>>(bsum, ptr, cursor);
    sort_kernel<<<eblocks, 256, 0, stream>>>(el, ew, flag, cursor, sorted);

    agg_kernel<<<(NSEG * 16 + 255) / 256 /* 50000 */, 256, 0, stream>>>(ptr, sorted, x, flag, num);

    dense_mfma_kernel<<<(N_NODES + 63) / 64, 256, 0, stream>>>((const uint16_t*)num, x, sWg, biasv, flag, d_out);
}

// Round 3
// 349.687 us; speedup vs baseline: 1.1158x; 1.1158x over previous
//
#include <hip/hip_runtime.h>
#include <stdint.h>

#define N_NODES 100000
#define N_EDGES 1600000
#define IN_DIM 32
#define OUT_DIM 64
#define N_REL 8
#define NSEG (N_NODES * N_REL)     // 800000
#define EPS 1e-10f
#define N_KK 9                      // K-tiles of 32 (8 rel + 1 self)
#define SWG_ELEMS (N_KK * 4 * 64 * 8)  // 18432 bf16 in b-frag order

// counting-sort scan geometry
#define SCAN_ELEMS 4096                         // elements per scan block (256 thr x 16)
#define SCAN_NB ((NSEG + SCAN_ELEMS - 1) / SCAN_ELEMS)  // 196 (fits one 256-thr block in pass 2)

// XCD slicing for the scatter: 8 slices of 12500 dst-nodes each.
#define N_XCD 8
#define NODES_PER_SLICE (N_NODES / N_XCD)       // 12500

typedef __attribute__((ext_vector_type(8))) short bf16x8;
typedef __attribute__((ext_vector_type(4))) float f32x4;

static __device__ __forceinline__ float bflo(uint32_t u) { return __uint_as_float(u << 16); }
static __device__ __forceinline__ float bfhi(uint32_t u) { return __uint_as_float(u & 0xffff0000u); }
static __device__ __forceinline__ uint16_t f2bf(float f) {
    uint32_t u = __float_as_uint(f);
    return (uint16_t)((u + 0x7fffu + ((u >> 16) & 1u)) >> 16); // RNE
}

// ---------------------------------------------------------------------------
// Dtype probe (earlier rounds proved fp32; kept for robustness, ~3us).
// ---------------------------------------------------------------------------
__global__ __launch_bounds__(256) void detect_kernel(const uint32_t* __restrict__ xw,
                                                     int* __restrict__ flag) {
    __shared__ int cnt;
    if (threadIdx.x == 0) cnt = 0;
    __syncthreads();
    int c = 0;
    for (int k = threadIdx.x; k < 4096; k += 256) {
        uint32_t w = xw[k];
        uint32_t e = (w >> 7) & 0xffu;
        c += (e >= 160u) ? 1 : 0;
    }
    atomicAdd(&cnt, c);
    __syncthreads();
    if (threadIdx.x == 0) *flag = (cnt > 64) ? 1 : 0;  // 1 = fp32 inputs
}

// ---------------------------------------------------------------------------
// prep: swizzle W = [Wl ; Ws] into b-frag order once. Fuses bias add.
// ---------------------------------------------------------------------------
__global__ __launch_bounds__(256) void prep_kernel(const void* __restrict__ Wl,
                                                   const void* __restrict__ Ws,
                                                   const void* __restrict__ bl,
                                                   const void* __restrict__ bs,
                                                   const int* __restrict__ flag,
                                                   uint16_t* __restrict__ sWg,
                                                   float* __restrict__ biasv) {
    int f32 = *flag;
    int idx = blockIdx.x * 256 + threadIdx.x;
    if (idx < SWG_ELEMS) {
        int j    = idx & 7;
        int lane = (idx >> 3) & 63;
        int ot   = (idx >> 9) & 3;
        int kk   = idx >> 11;
        int quad = lane >> 4;
        int k = kk * 32 + quad * 8 + j;
        int o = ot * 16 + (lane & 15);
        if (f32) {
            float v = (k < 256) ? ((const float*)Wl)[(size_t)k * OUT_DIM + o]
                                : ((const float*)Ws)[(size_t)(k - 256) * OUT_DIM + o];
            sWg[idx] = f2bf(v);
        } else {
            sWg[idx] = (k < 256) ? ((const uint16_t*)Wl)[(size_t)k * OUT_DIM + o]
                                 : ((const uint16_t*)Ws)[(size_t)(k - 256) * OUT_DIM + o];
        }
    } else if (idx < SWG_ELEMS + OUT_DIM) {
        int o = idx - SWG_ELEMS;
        if (f32) biasv[o] = ((const float*)bl)[o] + ((const float*)bs)[o];
        else     biasv[o] = bflo((uint32_t)((const uint16_t*)bl)[o])
                          + bflo((uint32_t)((const uint16_t*)bs)[o]);
    }
}

// ---------------------------------------------------------------------------
// xbf: one-time x -> bf16 row-major copy (12.8MB -> 6.4MB). Halves the
// gather traffic in agg and removes dtype branches from hot loops.
// ---------------------------------------------------------------------------
__global__ __launch_bounds__(256) void xbf_kernel(const void* __restrict__ x,
                                                  const int* __restrict__ flag,
                                                  uint16_t* __restrict__ xbf) {
    int i = blockIdx.x * 256 + threadIdx.x;       // one thread = 8 elements
    if (i >= N_NODES * IN_DIM / 8) return;
    if (*flag) {
        const float4 v0 = ((const float4*)x)[(size_t)i * 2];
        const float4 v1 = ((const float4*)x)[(size_t)i * 2 + 1];
        bf16x8 r;
        r[0] = (short)f2bf(v0.x); r[1] = (short)f2bf(v0.y);
        r[2] = (short)f2bf(v0.z); r[3] = (short)f2bf(v0.w);
        r[4] = (short)f2bf(v1.x); r[5] = (short)f2bf(v1.y);
        r[6] = (short)f2bf(v1.z); r[7] = (short)f2bf(v1.w);
        *(bf16x8*)(xbf + (size_t)i * 8) = r;
    } else {
        *(bf16x8*)(xbf + (size_t)i * 8) = ((const bf16x8*)x)[i];
    }
}

// ---------------------------------------------------------------------------
// CSR build step 1: histogram of segment sizes (1.6M no-return u32 atomics).
// ---------------------------------------------------------------------------
__global__ __launch_bounds__(256) void hist_kernel(const int* __restrict__ el,
                                                   uint32_t* __restrict__ cnt) {
    int e = blockIdx.x * 256 + threadIdx.x;
    if (e >= N_EDGES) return;
    int dst = el[e * 3 + 1];
    int rel = el[e * 3 + 2];
    atomicAdd(&cnt[dst * N_REL + rel], 1u);
}

// ---------------------------------------------------------------------------
// CSR build step 2a: per-block sums of counts (SCAN_ELEMS per block).
// ---------------------------------------------------------------------------
__global__ __launch_bounds__(256) void scan1_kernel(const uint32_t* __restrict__ cnt,
                                                    uint32_t* __restrict__ bsum) {
    int base = blockIdx.x * SCAN_ELEMS + threadIdx.x * 16;
    uint32_t s = 0;
    #pragma unroll
    for (int j = 0; j < 16; ++j) {
        int i = base + j;
        s += (i < NSEG) ? cnt[i] : 0u;
    }
    __shared__ uint32_t ls[256];
    ls[threadIdx.x] = s;
    __syncthreads();
    #pragma unroll
    for (int off = 128; off > 0; off >>= 1) {
        if (threadIdx.x < off) ls[threadIdx.x] += ls[threadIdx.x + off];
        __syncthreads();
    }
    if (threadIdx.x == 0) bsum[blockIdx.x] = ls[0];
}

// ---------------------------------------------------------------------------
// CSR build step 2b: exclusive scan of the SCAN_NB (=196) block sums.
// ---------------------------------------------------------------------------
__global__ __launch_bounds__(256) void scan2_kernel(uint32_t* __restrict__ bsum) {
    __shared__ uint32_t ls[256];
    int tid = threadIdx.x;
    ls[tid] = (tid < SCAN_NB) ? bsum[tid] : 0u;
    __syncthreads();
    if (tid == 0) {
        uint32_t run = 0;
        for (int i = 0; i < SCAN_NB; ++i) { uint32_t c = ls[i]; ls[i] = run; run += c; }
    }
    __syncthreads();
    if (tid < SCAN_NB) bsum[tid] = ls[tid];
}

// ---------------------------------------------------------------------------
// CSR build step 2c: in-block exclusive scan + block offset -> ptr & cursor.
// ---------------------------------------------------------------------------
__global__ __launch_bounds__(256) void scan3_kernel(const uint32_t* __restrict__ bsum,
                                                    uint32_t* __restrict__ ptr,
                                                    uint32_t* __restrict__ cursor) {
    int tid = threadIdx.x;
    int base = blockIdx.x * SCAN_ELEMS + tid * 16;
    uint32_t v[16];
    uint32_t run = 0;
    #pragma unroll
    for (int j = 0; j < 16; ++j) {
        int i = base + j;
        uint32_t c = (i < NSEG) ? cursor[i] : 0u;  // cursor currently holds counts
        v[j] = run;
        run += c;
    }
    __shared__ uint32_t ls[256];
    ls[tid] = run;
    __syncthreads();
    // Hillis-Steele inclusive scan over 256 thread totals
    for (int off = 1; off < 256; off <<= 1) {
        uint32_t t = (tid >= off) ? ls[tid - off] : 0u;
        __syncthreads();
        ls[tid] += t;
        __syncthreads();
    }
    uint32_t texcl = ls[tid] - run;
    uint32_t boff = bsum[blockIdx.x];
    #pragma unroll
    for (int j = 0; j < 16; ++j) {
        int i = base + j;
        if (i < NSEG) {
            uint32_t val = boff + texcl + v[j];
            ptr[i]    = val;
            cursor[i] = val;   // running cursor for the sort pass
        }
    }
    if (blockIdx.x == 0 && tid == 0) ptr[NSEG] = N_EDGES;
}

// ---------------------------------------------------------------------------
// CSR build step 3: XCD-sliced scatter. blockIdx%8 round-robins across the
// 8 XCDs (measured: learn_hip m09/T1), so block b keeps only edges with
// dst in slice b&7 -> each XCD's writes hit a contiguous 1.6MB region of
// `sorted` that FITS ITS 4MB L2 -> ~8 stores/line combine before writeback.
// (Round-2 evidence: unsliced scatter wrote 103.8MB HBM for 12.8MB of data.)
// el re-read 8x is L3-served (19MB << 256MB).
// ---------------------------------------------------------------------------
__global__ __launch_bounds__(256) void sort_kernel(const int* __restrict__ el,
                                                   const void* __restrict__ ew,
                                                   const int* __restrict__ flag,
                                                   uint32_t* __restrict__ cursor,
                                                   uint2* __restrict__ sorted) {
    int b = blockIdx.x;
    int tile  = b >> 3;
    int slice = b & 7;
    int e = tile * 256 + threadIdx.x;
    if (e >= N_EDGES) return;
    int dst = el[e * 3 + 1];
    if (dst / NODES_PER_SLICE != slice) return;   // magic-mul div by 12500
    int src = el[e * 3 + 0];
    int rel = el[e * 3 + 2];
    float w = (*flag) ? ((const float*)ew)[e]
                      : bflo((uint32_t)((const uint16_t*)ew)[e]);
    int seg = dst * N_REL + rel;
    uint32_t pos = atomicAdd(&cursor[seg], 1u);
    sorted[pos] = make_uint2((uint32_t)src, __float_as_uint(w));
}

// ---------------------------------------------------------------------------
// Gather-aggregate: 16 lanes per segment, fp32 accumulation in registers,
// fused 1/(den+eps) normalization, single coalesced bf16 write per segment.
// ZERO atomics. Gathers read bf16 x rows (64B/edge, halved vs fp32).
// ---------------------------------------------------------------------------
__global__ __launch_bounds__(256) void agg_kernel(const uint32_t* __restrict__ ptr,
                                                  const uint2* __restrict__ sorted,
                                                  const uint16_t* __restrict__ xbf,
                                                  uint32_t* __restrict__ num) {
    int t = blockIdx.x * 256 + threadIdx.x;
    int g = t >> 4;          // segment id
    int p = t & 15;          // feature-pair index
    if (g >= NSEG) return;
    int beg = (int)ptr[g];
    int end = (int)ptr[g + 1];
    float a0 = 0.f, a1 = 0.f, sw = 0.f;
    for (int i = beg; i < end; ++i) {
        uint2 d = sorted[i];                     // broadcast across the 16 lanes
        float w = __uint_as_float(d.y);
        uint32_t u = *(const uint32_t*)(xbf + (size_t)d.x * IN_DIM + 2 * p);
        a0 += w * bflo(u);
        a1 += w * bfhi(u);
        sw += w;
    }
    float inv = 1.0f / (sw + EPS);               // empty segment -> 0/(eps) = 0
    uint32_t packed = (uint32_t)f2bf(a0 * inv) | ((uint32_t)f2bf(a1 * inv) << 16);
    num[(size_t)g * 16 + p] = packed;
}

// ---------------------------------------------------------------------------
// Dense MFMA GEMM: C[100000x64] = [norm_num | xbf] * W + bias, relu.
// num is already normalized bf16 -> A-fragments are straight bf16x8 loads.
// MFMA layouts (HW-verified): A[m=lane&15][k=quad*8+j]; B[k][n=lane&15];
// C row=quad*4+reg, col=lane&15.
// ---------------------------------------------------------------------------
__global__ __launch_bounds__(256) void dense_mfma_kernel(
    const uint16_t* __restrict__ num16,
    const uint16_t* __restrict__ xbf,
    const uint16_t* __restrict__ sWg,
    const float* __restrict__ biasv,
    const int* __restrict__ flag,
    void* __restrict__ out)
{
    __shared__ uint16_t sB[SWG_ELEMS]; // 36KB
    int f32 = *flag;

    #pragma unroll
    for (int it = 0; it < SWG_ELEMS / (256 * 8); ++it) {   // 9 iterations
        int idx = (it * 256 + threadIdx.x) * 8;
        *(bf16x8*)(sB + idx) = *(const bf16x8*)(sWg + idx);
    }
    __syncthreads();

    int wid  = threadIdx.x >> 6;
    int lane = threadIdx.x & 63;
    int quad = lane >> 4;
    int m    = lane & 15;

    int n0 = blockIdx.x * 64 + wid * 16;
    int n  = n0 + m;
    int nc = (n < N_NODES) ? n : (N_NODES - 1);

    float bias[4];
    #pragma unroll
    for (int ot = 0; ot < 4; ++ot) bias[ot] = biasv[ot * 16 + m];

    f32x4 acc[4];
    #pragma unroll
    for (int ot = 0; ot < 4; ++ot) acc[ot] = (f32x4){0.f, 0.f, 0.f, 0.f};

    #pragma unroll
    for (int kk = 0; kk < N_KK; ++kk) {
        bf16x8 a;
        if (kk < 8) {
            a = *(const bf16x8*)(num16 + ((size_t)nc * 8 + kk) * 32 + quad * 8);
        } else {
            a = *(const bf16x8*)(xbf + (size_t)nc * IN_DIM + quad * 8);
        }
        #pragma unroll
        for (int ot = 0; ot < 4; ++ot) {
            bf16x8 b = *(const bf16x8*)(sB + ((kk * 4 + ot) * 64 + lane) * 8);
            acc[ot] = __builtin_amdgcn_mfma_f32_16x16x32_bf16(a, b, acc[ot], 0, 0, 0);
        }
    }

    #pragma unroll
    for (int ot = 0; ot < 4; ++ot) {
        #pragma unroll
        for (int reg = 0; reg < 4; ++reg) {
            int node = n0 + quad * 4 + reg;
            if (node >= N_NODES) continue;
            int o = ot * 16 + m;
            float v = fmaxf(acc[ot][reg] + bias[ot], 0.0f);
            if (f32) ((float*)out)[(size_t)node * OUT_DIM + o] = v;
            else     ((uint16_t*)out)[(size_t)node * OUT_DIM + o] = f2bf(v);
        }
    }
}

// ===========================================================================
extern "C" void kernel_launch(void* const* d_in, const int* in_sizes, int n_in,
                              void* d_out, int out_size, void* d_ws, size_t ws_size,
                              hipStream_t stream) {
    const void* x  = d_in[0];
    const int* el  = (const int*)d_in[1];
    const void* ew = d_in[2];
    const void* Wl = d_in[3];
    const void* bl = d_in[4];
    const void* Ws = d_in[5];
    const void* bs = d_in[6];

    // workspace:
    // [flag 64B][ptr (NSEG+1)*4][cursor NSEG*4][bsum 16KB][sorted 12.8MB]
    // [num 51.2MB bf16][sWg 36KB][biasv 256B][xbf 6.4MB]   total ~77MB
    const size_t OFF_PTR  = 64;
    const size_t OFF_CUR  = OFF_PTR + (((size_t)(NSEG + 1) * 4 + 63) & ~(size_t)63);
    const size_t OFF_BS   = OFF_CUR + (size_t)NSEG * 4;
    const size_t OFF_SORT = OFF_BS + 16384;
    const size_t OFF_NUM  = OFF_SORT + (size_t)N_EDGES * 8;
    const size_t OFF_SWG  = OFF_NUM + (size_t)NSEG * IN_DIM * 2;
    const size_t OFF_BIAS = OFF_SWG + (size_t)SWG_ELEMS * 2;
    const size_t OFF_XBF  = OFF_BIAS + 256;
    const size_t REQ      = OFF_XBF + (size_t)N_NODES * IN_DIM * 2;
    if (ws_size < REQ) return;

    int*      flag   = (int*)d_ws;
    uint32_t* ptr    = (uint32_t*)((char*)d_ws + OFF_PTR);
    uint32_t* cursor = (uint32_t*)((char*)d_ws + OFF_CUR);
    uint32_t* bsum   = (uint32_t*)((char*)d_ws + OFF_BS);
    uint2*    sorted = (uint2*)((char*)d_ws + OFF_SORT);
    uint32_t* num    = (uint32_t*)((char*)d_ws + OFF_NUM);
    uint16_t* sWg    = (uint16_t*)((char*)d_ws + OFF_SWG);
    float*    biasv  = (float*)((char*)d_ws + OFF_BIAS);
    uint16_t* xbf    = (uint16_t*)((char*)d_ws + OFF_XBF);

    // only the histogram bins need zeroing (3.2MB)
    (void)hipMemsetAsync(cursor, 0, (size_t)NSEG * 4, stream);

    detect_kernel<<<1, 256, 0, stream>>>((const uint32_t*)x, flag);
    prep_kernel<<<(SWG_ELEMS + OUT_DIM + 255) / 256, 256, 0, stream>>>(Wl, Ws, bl, bs, flag, sWg, biasv);
    xbf_kernel<<<(N_NODES * IN_DIM / 8 + 255) / 256, 256, 0, stream>>>(x, flag, xbf);

    const int eblocks = (N_EDGES + 255) / 256;  // 6250
    hist_kernel<<<eblocks, 256, 0, stream>>>(el, cursor);
    scan1_kernel<<<SCAN_NB, 256, 0, stream>>>(cursor, bsum);
    scan2_kernel<<<1, 256, 0, stream>>>(bsum);
    scan3_kernel<<<SCAN_NB, 256, 0, stream>>>(bsum, ptr, cursor);
    sort_kernel<<<eblocks * N_XCD, 256, 0, stream>>>(el, ew, flag, cursor, sorted);

    agg_kernel<<<(NSEG * 16 + 255) / 256 /* 50000 */, 256, 0, stream>>>(ptr, sorted, xbf, num);

    dense_mfma_kernel<<<(N_NODES + 63) / 64, 256, 0, stream>>>((const uint16_t*)num, xbf, sWg, biasv, flag, d_out);
}

// Round 4
// 319.417 us; speedup vs baseline: 1.2216x; 1.0948x over previous
//
#include <hip/hip_runtime.h>
#include <stdint.h>

#define N_NODES 100000
#define N_EDGES 1600000
#define IN_DIM 32
#define OUT_DIM 64
#define N_REL 8
#define NSEG (N_NODES * N_REL)     // 800000
#define EPS 1e-10f
#define N_KK 9                      // K-tiles of 32 (8 rel + 1 self)
#define SWG_ELEMS (N_KK * 4 * 64 * 8)  // 18432 bf16 in b-frag order

// counting-sort scan geometry
#define SCAN_ELEMS 4096                         // elements per scan block (256 thr x 16)
#define SCAN_NB ((NSEG + SCAN_ELEMS - 1) / SCAN_ELEMS)  // 196 (fits one 256-thr block in pass 2)

// XCD slicing for the scatter: 8 slices of 12500 dst-nodes each.
#define N_XCD 8
#define NODES_PER_SLICE (N_NODES / N_XCD)       // 12500

typedef __attribute__((ext_vector_type(8))) short bf16x8;
typedef __attribute__((ext_vector_type(4))) float f32x4;

static __device__ __forceinline__ float bflo(uint32_t u) { return __uint_as_float(u << 16); }
static __device__ __forceinline__ float bfhi(uint32_t u) { return __uint_as_float(u & 0xffff0000u); }
static __device__ __forceinline__ uint16_t f2bf(float f) {
    uint32_t u = __float_as_uint(f);
    return (uint16_t)((u + 0x7fffu + ((u >> 16) & 1u)) >> 16); // RNE
}

// ---------------------------------------------------------------------------
// Dtype probe (earlier rounds proved fp32; kept for robustness, ~3us).
// ---------------------------------------------------------------------------
__global__ __launch_bounds__(256) void detect_kernel(const uint32_t* __restrict__ xw,
                                                     int* __restrict__ flag) {
    __shared__ int cnt;
    if (threadIdx.x == 0) cnt = 0;
    __syncthreads();
    int c = 0;
    for (int k = threadIdx.x; k < 4096; k += 256) {
        uint32_t w = xw[k];
        uint32_t e = (w >> 7) & 0xffu;
        c += (e >= 160u) ? 1 : 0;
    }
    atomicAdd(&cnt, c);
    __syncthreads();
    if (threadIdx.x == 0) *flag = (cnt > 64) ? 1 : 0;  // 1 = fp32 inputs
}

// ---------------------------------------------------------------------------
// prep: swizzle W = [Wl ; Ws] into b-frag order once. Fuses bias add.
// ---------------------------------------------------------------------------
__global__ __launch_bounds__(256) void prep_kernel(const void* __restrict__ Wl,
                                                   const void* __restrict__ Ws,
                                                   const void* __restrict__ bl,
                                                   const void* __restrict__ bs,
                                                   const int* __restrict__ flag,
                                                   uint16_t* __restrict__ sWg,
                                                   float* __restrict__ biasv) {
    int f32 = *flag;
    int idx = blockIdx.x * 256 + threadIdx.x;
    if (idx < SWG_ELEMS) {
        int j    = idx & 7;
        int lane = (idx >> 3) & 63;
        int ot   = (idx >> 9) & 3;
        int kk   = idx >> 11;
        int quad = lane >> 4;
        int k = kk * 32 + quad * 8 + j;
        int o = ot * 16 + (lane & 15);
        if (f32) {
            float v = (k < 256) ? ((const float*)Wl)[(size_t)k * OUT_DIM + o]
                                : ((const float*)Ws)[(size_t)(k - 256) * OUT_DIM + o];
            sWg[idx] = f2bf(v);
        } else {
            sWg[idx] = (k < 256) ? ((const uint16_t*)Wl)[(size_t)k * OUT_DIM + o]
                                 : ((const uint16_t*)Ws)[(size_t)(k - 256) * OUT_DIM + o];
        }
    } else if (idx < SWG_ELEMS + OUT_DIM) {
        int o = idx - SWG_ELEMS;
        if (f32) biasv[o] = ((const float*)bl)[o] + ((const float*)bs)[o];
        else     biasv[o] = bflo((uint32_t)((const uint16_t*)bl)[o])
                          + bflo((uint32_t)((const uint16_t*)bs)[o]);
    }
}

// ---------------------------------------------------------------------------
// xbf: one-time x -> bf16 row-major copy (12.8MB -> 6.4MB). Halves the
// gather traffic and removes dtype branches from hot loops.
// ---------------------------------------------------------------------------
__global__ __launch_bounds__(256) void xbf_kernel(const void* __restrict__ x,
                                                  const int* __restrict__ flag,
                                                  uint16_t* __restrict__ xbf) {
    int i = blockIdx.x * 256 + threadIdx.x;       // one thread = 8 elements
    if (i >= N_NODES * IN_DIM / 8) return;
    if (*flag) {
        const float4 v0 = ((const float4*)x)[(size_t)i * 2];
        const float4 v1 = ((const float4*)x)[(size_t)i * 2 + 1];
        bf16x8 r;
        r[0] = (short)f2bf(v0.x); r[1] = (short)f2bf(v0.y);
        r[2] = (short)f2bf(v0.z); r[3] = (short)f2bf(v0.w);
        r[4] = (short)f2bf(v1.x); r[5] = (short)f2bf(v1.y);
        r[6] = (short)f2bf(v1.z); r[7] = (short)f2bf(v1.w);
        *(bf16x8*)(xbf + (size_t)i * 8) = r;
    } else {
        *(bf16x8*)(xbf + (size_t)i * 8) = ((const bf16x8*)x)[i];
    }
}

// ---------------------------------------------------------------------------
// CSR build step 1: histogram of segment sizes (1.6M no-return u32 atomics).
// ---------------------------------------------------------------------------
__global__ __launch_bounds__(256) void hist_kernel(const int* __restrict__ el,
                                                   uint32_t* __restrict__ cnt) {
    int e = blockIdx.x * 256 + threadIdx.x;
    if (e >= N_EDGES) return;
    int dst = el[e * 3 + 1];
    int rel = el[e * 3 + 2];
    atomicAdd(&cnt[dst * N_REL + rel], 1u);
}

// ---------------------------------------------------------------------------
// CSR build step 2a: per-block sums of counts (SCAN_ELEMS per block).
// ---------------------------------------------------------------------------
__global__ __launch_bounds__(256) void scan1_kernel(const uint32_t* __restrict__ cnt,
                                                    uint32_t* __restrict__ bsum) {
    int base = blockIdx.x * SCAN_ELEMS + threadIdx.x * 16;
    uint32_t s = 0;
    #pragma unroll
    for (int j = 0; j < 16; ++j) {
        int i = base + j;
        s += (i < NSEG) ? cnt[i] : 0u;
    }
    __shared__ uint32_t ls[256];
    ls[threadIdx.x] = s;
    __syncthreads();
    #pragma unroll
    for (int off = 128; off > 0; off >>= 1) {
        if (threadIdx.x < off) ls[threadIdx.x] += ls[threadIdx.x + off];
        __syncthreads();
    }
    if (threadIdx.x == 0) bsum[blockIdx.x] = ls[0];
}

// ---------------------------------------------------------------------------
// CSR build step 2b: exclusive scan of the SCAN_NB (=196) block sums.
// ---------------------------------------------------------------------------
__global__ __launch_bounds__(256) void scan2_kernel(uint32_t* __restrict__ bsum) {
    __shared__ uint32_t ls[256];
    int tid = threadIdx.x;
    ls[tid] = (tid < SCAN_NB) ? bsum[tid] : 0u;
    __syncthreads();
    if (tid == 0) {
        uint32_t run = 0;
        for (int i = 0; i < SCAN_NB; ++i) { uint32_t c = ls[i]; ls[i] = run; run += c; }
    }
    __syncthreads();
    if (tid < SCAN_NB) bsum[tid] = ls[tid];
}

// ---------------------------------------------------------------------------
// CSR build step 2c: in-block exclusive scan + block offset -> ptr & cursor.
// ---------------------------------------------------------------------------
__global__ __launch_bounds__(256) void scan3_kernel(const uint32_t* __restrict__ bsum,
                                                    uint32_t* __restrict__ ptr,
                                                    uint32_t* __restrict__ cursor) {
    int tid = threadIdx.x;
    int base = blockIdx.x * SCAN_ELEMS + tid * 16;
    uint32_t v[16];
    uint32_t run = 0;
    #pragma unroll
    for (int j = 0; j < 16; ++j) {
        int i = base + j;
        uint32_t c = (i < NSEG) ? cursor[i] : 0u;  // cursor currently holds counts
        v[j] = run;
        run += c;
    }
    __shared__ uint32_t ls[256];
    ls[tid] = run;
    __syncthreads();
    // Hillis-Steele inclusive scan over 256 thread totals
    for (int off = 1; off < 256; off <<= 1) {
        uint32_t t = (tid >= off) ? ls[tid - off] : 0u;
        __syncthreads();
        ls[tid] += t;
        __syncthreads();
    }
    uint32_t texcl = ls[tid] - run;
    uint32_t boff = bsum[blockIdx.x];
    #pragma unroll
    for (int j = 0; j < 16; ++j) {
        int i = base + j;
        if (i < NSEG) {
            uint32_t val = boff + texcl + v[j];
            ptr[i]    = val;
            cursor[i] = val;   // running cursor for the sort pass
        }
    }
    if (blockIdx.x == 0 && tid == 0) ptr[NSEG] = N_EDGES;
}

// ---------------------------------------------------------------------------
// CSR build step 3: XCD-sliced scatter (round-3 measured: 88us, faster than
// unsliced 115us, though write-amp persists -- L2 evictions from the el
// read stream defeat write combining; partition-first is the future fix).
// ---------------------------------------------------------------------------
__global__ __launch_bounds__(256) void sort_kernel(const int* __restrict__ el,
                                                   const void* __restrict__ ew,
                                                   const int* __restrict__ flag,
                                                   uint32_t* __restrict__ cursor,
                                                   uint2* __restrict__ sorted) {
    int b = blockIdx.x;
    int tile  = b >> 3;
    int slice = b & 7;
    int e = tile * 256 + threadIdx.x;
    if (e >= N_EDGES) return;
    int dst = el[e * 3 + 1];
    if (dst / NODES_PER_SLICE != slice) return;
    int src = el[e * 3 + 0];
    int rel = el[e * 3 + 2];
    float w = (*flag) ? ((const float*)ew)[e]
                      : bflo((uint32_t)((const uint16_t*)ew)[e]);
    int seg = dst * N_REL + rel;
    uint32_t pos = atomicAdd(&cursor[seg], 1u);
    sorted[pos] = make_uint2((uint32_t)src, __float_as_uint(w));
}

// ---------------------------------------------------------------------------
// FUSED gather-aggregate + dense MFMA. Key insight: lane l of wave w needs
// A-frag elements [node=n0+w*16+(l&15)][k=(l>>4)*8+j] -- exactly 8 features
// of one (node,rel) segment. So each lane gathers its segment's edges,
// accumulates fp32 in registers, normalizes, packs bf16x8, and MFMAs
// directly. `num` (51.2MB write + read) is never materialized.
// MFMA layouts (HW-verified): A[m=lane&15][k=quad*8+j]; B[k][n=lane&15];
// C row=quad*4+reg, col=lane&15.
// ---------------------------------------------------------------------------
__global__ __launch_bounds__(256) void fused_dense_kernel(
    const uint32_t* __restrict__ ptr,
    const uint2* __restrict__ sorted,
    const uint16_t* __restrict__ xbf,
    const uint16_t* __restrict__ sWg,
    const float* __restrict__ biasv,
    const int* __restrict__ flag,
    void* __restrict__ out)
{
    __shared__ uint16_t sB[SWG_ELEMS]; // 36KB
    int f32 = *flag;

    #pragma unroll
    for (int it = 0; it < SWG_ELEMS / (256 * 8); ++it) {   // 9 iterations
        int idx = (it * 256 + threadIdx.x) * 8;
        *(bf16x8*)(sB + idx) = *(const bf16x8*)(sWg + idx);
    }
    __syncthreads();

    int wid  = threadIdx.x >> 6;
    int lane = threadIdx.x & 63;
    int quad = lane >> 4;
    int m    = lane & 15;

    int n0 = blockIdx.x * 64 + wid * 16;
    int n  = n0 + m;
    int nc = (n < N_NODES) ? n : (N_NODES - 1);

    float bias[4];
    #pragma unroll
    for (int ot = 0; ot < 4; ++ot) bias[ot] = biasv[ot * 16 + m];

    f32x4 acc[4];
    #pragma unroll
    for (int ot = 0; ot < 4; ++ot) acc[ot] = (f32x4){0.f, 0.f, 0.f, 0.f};

    #pragma unroll
    for (int kk = 0; kk < N_KK; ++kk) {
        bf16x8 a;
        if (kk < 8) {
            // gather-aggregate this lane's segment (node nc, relation kk),
            // features [quad*8, quad*8+8)
            int seg = nc * N_REL + kk;
            int beg = (int)ptr[seg];
            int end = (int)ptr[seg + 1];
            float s0 = 0.f, s1 = 0.f, s2 = 0.f, s3 = 0.f;
            float s4 = 0.f, s5 = 0.f, s6 = 0.f, s7 = 0.f, sw = 0.f;
            for (int i = beg; i < end; ++i) {
                uint2 d = sorted[i];             // shared by the 4 quads of node nc
                float w = __uint_as_float(d.y);
                const uint4 xv = *(const uint4*)(xbf + (size_t)d.x * IN_DIM + quad * 8);
                s0 += w * bflo(xv.x); s1 += w * bfhi(xv.x);
                s2 += w * bflo(xv.y); s3 += w * bfhi(xv.y);
                s4 += w * bflo(xv.z); s5 += w * bfhi(xv.z);
                s6 += w * bflo(xv.w); s7 += w * bfhi(xv.w);
                sw += w;
            }
            float inv = 1.0f / (sw + EPS);       // empty segment -> 0
            a[0] = (short)f2bf(s0 * inv); a[1] = (short)f2bf(s1 * inv);
            a[2] = (short)f2bf(s2 * inv); a[3] = (short)f2bf(s3 * inv);
            a[4] = (short)f2bf(s4 * inv); a[5] = (short)f2bf(s5 * inv);
            a[6] = (short)f2bf(s6 * inv); a[7] = (short)f2bf(s7 * inv);
        } else {
            a = *(const bf16x8*)(xbf + (size_t)nc * IN_DIM + quad * 8);
        }
        #pragma unroll
        for (int ot = 0; ot < 4; ++ot) {
            bf16x8 b = *(const bf16x8*)(sB + ((kk * 4 + ot) * 64 + lane) * 8);
            acc[ot] = __builtin_amdgcn_mfma_f32_16x16x32_bf16(a, b, acc[ot], 0, 0, 0);
        }
    }

    #pragma unroll
    for (int ot = 0; ot < 4; ++ot) {
        #pragma unroll
        for (int reg = 0; reg < 4; ++reg) {
            int node = n0 + quad * 4 + reg;
            if (node >= N_NODES) continue;
            int o = ot * 16 + m;
            float v = fmaxf(acc[ot][reg] + bias[ot], 0.0f);
            if (f32) ((float*)out)[(size_t)node * OUT_DIM + o] = v;
            else     ((uint16_t*)out)[(size_t)node * OUT_DIM + o] = f2bf(v);
        }
    }
}

// ===========================================================================
extern "C" void kernel_launch(void* const* d_in, const int* in_sizes, int n_in,
                              void* d_out, int out_size, void* d_ws, size_t ws_size,
                              hipStream_t stream) {
    const void* x  = d_in[0];
    const int* el  = (const int*)d_in[1];
    const void* ew = d_in[2];
    const void* Wl = d_in[3];
    const void* bl = d_in[4];
    const void* Ws = d_in[5];
    const void* bs = d_in[6];

    // workspace:
    // [flag 64B][ptr (NSEG+1)*4][cursor NSEG*4][bsum 16KB][sorted 12.8MB]
    // [sWg 36KB][biasv 256B][xbf 6.4MB]   total ~25.7MB (num eliminated)
    const size_t OFF_PTR  = 64;
    const size_t OFF_CUR  = OFF_PTR + (((size_t)(NSEG + 1) * 4 + 63) & ~(size_t)63);
    const size_t OFF_BS   = OFF_CUR + (size_t)NSEG * 4;
    const size_t OFF_SORT = OFF_BS + 16384;
    const size_t OFF_SWG  = OFF_SORT + (size_t)N_EDGES * 8;
    const size_t OFF_BIAS = OFF_SWG + (size_t)SWG_ELEMS * 2;
    const size_t OFF_XBF  = OFF_BIAS + 256;
    const size_t REQ      = OFF_XBF + (size_t)N_NODES * IN_DIM * 2;
    if (ws_size < REQ) return;

    int*      flag   = (int*)d_ws;
    uint32_t* ptr    = (uint32_t*)((char*)d_ws + OFF_PTR);
    uint32_t* cursor = (uint32_t*)((char*)d_ws + OFF_CUR);
    uint32_t* bsum   = (uint32_t*)((char*)d_ws + OFF_BS);
    uint2*    sorted = (uint2*)((char*)d_ws + OFF_SORT);
    uint16_t* sWg    = (uint16_t*)((char*)d_ws + OFF_SWG);
    float*    biasv  = (float*)((char*)d_ws + OFF_BIAS);
    uint16_t* xbf    = (uint16_t*)((char*)d_ws + OFF_XBF);

    // only the histogram bins need zeroing (3.2MB)
    (void)hipMemsetAsync(cursor, 0, (size_t)NSEG * 4, stream);

    detect_kernel<<<1, 256, 0, stream>>>((const uint32_t*)x, flag);
    prep_kernel<<<(SWG_ELEMS + OUT_DIM + 255) / 256, 256, 0, stream>>>(Wl, Ws, bl, bs, flag, sWg, biasv);
    xbf_kernel<<<(N_NODES * IN_DIM / 8 + 255) / 256, 256, 0, stream>>>(x, flag, xbf);

    const int eblocks = (N_EDGES + 255) / 256;  // 6250
    hist_kernel<<<eblocks, 256, 0, stream>>>(el, cursor);
    scan1_kernel<<<SCAN_NB, 256, 0, stream>>>(cursor, bsum);
    scan2_kernel<<<1, 256, 0, stream>>>(bsum);
    scan3_kernel<<<SCAN_NB, 256, 0, stream>>>(bsum, ptr, cursor);
    sort_kernel<<<eblocks * N_XCD, 256, 0, stream>>>(el, ew, flag, cursor, sorted);

    fused_dense_kernel<<<(N_NODES + 63) / 64, 256, 0, stream>>>(ptr, sorted, xbf, sWg, biasv, flag, d_out);
}